// Round 18
// baseline (106.944 us; speedup 1.0000x reference)
//
#include <hip/hip_runtime.h>
#include <utility>

#define D_DIM 256
#define WID   33
#define CEN   16
#define RWAVE 32                   // rows per wave
#define RBLK  64                   // rows per block (2 row-groups x 2 col-halves)
#define WINW  65                   // window positions 0..64 (rel. to base)
#define PRE   49                   // head loads 0..48; row k issues 49+k

// R17 (75.4us): float2 columns halved VALU+mem instrs; VGPR 64, no spill.
// Remaining gap vs 41us BW floor is exposed latency: steady-state only ~9
// dwordx2 outstanding/wave (~60KB/CU -> ~2TB/s MLP cap). Single change:
// lookahead 9 -> 17 rows (PRE 41 -> 49). Live window ~50 f32x2 ~= 100 VGPR,
// fits the (256,4) 128 budget. Spill tripwire: WRITE must stay ~131MB.

typedef float f32x2 __attribute__((ext_vector_type(2)));

__device__ __forceinline__ float rdlane(float v, int l) {
    return __uint_as_float(__builtin_amdgcn_readlane(__float_as_uint(v), l));
}

__device__ __forceinline__ int clampN(int p, int N) {
    return p < 0 ? 0 : (p >= N ? N - 1 : p);
}

__device__ __forceinline__ f32x2 ld2(const float* __restrict__ p) {
    return *(const f32x2*)p;
}

template <size_t... Is>
__device__ __forceinline__ void load_head(f32x2 (&W)[WINW],
                                          const float* __restrict__ xw,
                                          int base, int N,
                                          std::index_sequence<Is...>) {
    ((W[Is] = ld2(xw + (size_t)clampN(base + (int)Is, N) * D_DIM)), ...);
}

template <size_t... Rs>
__device__ __forceinline__ void load_w(float (&wvv)[RWAVE],
                                       const float* __restrict__ smb,
                                       int n0w, int minl,
                                       std::index_sequence<Rs...>) {
    ((wvv[Rs] = smb[(size_t)(n0w + (int)Rs) * WID + minl]), ...);
}

template <size_t... Rs>
__device__ __forceinline__ void zero_bad_w(float (&wvv)[RWAVE], int n0w, int lane,
                                           int N, std::index_sequence<Rs...>) {
    ((wvv[Rs] = ((unsigned)(n0w + (int)Rs - CEN + lane) < (unsigned)N)
                    ? wvv[Rs] : 0.0f),
     ...);
}

template <int K, size_t... Is>
__device__ __forceinline__ f32x2 dot_row(const f32x2 (&W)[WINW], float wrow,
                                         std::index_sequence<Is...>) {
    f32x2 a0 = {0.f, 0.f}, a1 = {0.f, 0.f}, a2 = {0.f, 0.f}, a3 = {0.f, 0.f};
    (([&] {
         const float ws = rdlane(wrow, (int)Is);
         const f32x2 xv = W[K + (int)Is];
         f32x2& ac = ((int)Is & 3) == 0 ? a0
                   : ((int)Is & 3) == 1 ? a1
                   : ((int)Is & 3) == 2 ? a2 : a3;
         ac.x = fmaf(xv.x, ws, ac.x);
         ac.y = fmaf(xv.y, ws, ac.y);
     }()),
     ...);
    return (a0 + a1) + (a2 + a3);
}

template <int K>
__device__ __forceinline__ void row_step(f32x2 (&W)[WINW], const float (&wvv)[RWAVE],
                                         float szv, float* __restrict__ ob,
                                         const float* __restrict__ xw,
                                         int base, int N) {
    if constexpr (PRE + K < WINW) {        // pipelined load, 17-row lookahead
        const int p = base + PRE + K;      // >= 33, only upper clamp needed
        W[PRE + K] = ld2(xw + (size_t)(p >= N ? N - 1 : p) * D_DIM);
    }
    __builtin_amdgcn_sched_barrier(0);     // pin: no sinking across rows
    const f32x2 s   = dot_row<K>(W, wvv[K], std::make_index_sequence<WID>{});
    const float inv = __builtin_amdgcn_rcpf(fmaxf(rdlane(szv, K), 1e-6f));
    f32x2 o;
    o.x = s.x * inv;
    o.y = s.y * inv;
    *(f32x2*)(ob + (size_t)K * D_DIM) = o;
}

template <size_t... Ks>
__device__ __forceinline__ void all_rows(f32x2 (&W)[WINW], const float (&wvv)[RWAVE],
                                         float szv, float* __restrict__ ob,
                                         const float* __restrict__ xw,
                                         int base, int N,
                                         std::index_sequence<Ks...>) {
    (row_step<(int)Ks>(W, wvv, szv, ob, xw, base, N), ...);
}

__global__ __launch_bounds__(256, 4) void local_enc_kernel(
    const float* __restrict__ x, const float* __restrict__ sizev,
    const float* __restrict__ sm, float* __restrict__ out, int N) {
    // XCD swizzle: XCD k owns batch k, strips consecutive -> halo L2-local
    const int bid   = blockIdx.x;
    const int swz   = (bid & 7) * 256 + (bid >> 3);
    const int strip = swz & 255;
    const int b     = swz >> 8;
    const int n0    = strip * RBLK;
    const int tid   = threadIdx.x;
    const int wv    = tid >> 6;
    const int lane  = tid & 63;

    const int n0w = n0 + RWAVE * (wv >> 1);        // this wave's 32 rows
    const int cp  = ((wv & 1) * 64 + lane) * 2;    // this thread's column pair

    const size_t bN = (size_t)b * (size_t)N;
    const float* __restrict__ xw  = x   + bN * D_DIM + cp;
    float*       __restrict__ ob  = out + (bN + (size_t)n0w) * D_DIM + cp;
    const float* __restrict__ smb = sm    + bN * WID;
    const float* __restrict__ szb = sizev + bN;

    const int minl = (lane < WID) ? lane : (WID - 1);
    const float szv = szb[(n0w + minl < N) ? (n0w + minl) : (N - 1)];

    float wvv[RWAVE];
    load_w(wvv, smb, n0w, minl, std::make_index_sequence<RWAVE>{});
    if (n0w < CEN || n0w + RWAVE - 1 + CEN >= N)   // boundary waves only
        zero_bad_w(wvv, n0w, lane, N, std::make_index_sequence<RWAVE>{});

    const int base = n0w - CEN;
    f32x2 W[WINW];
    load_head(W, xw, base, N, std::make_index_sequence<PRE>{});

    __builtin_amdgcn_sched_barrier(0);
    all_rows(W, wvv, szv, ob, xw, base, N, std::make_index_sequence<RWAVE>{});
}

extern "C" void kernel_launch(void* const* d_in, const int* in_sizes, int n_in,
                              void* d_out, int out_size, void* d_ws, size_t ws_size,
                              hipStream_t stream) {
    const float* x  = (const float*)d_in[0];
    const float* sz = (const float*)d_in[1];
    const float* sm = (const float*)d_in[2];
    float* out = (float*)d_out;

    const int B = 8;
    const int N = 16384;

    dim3 grid((N / RBLK) * B, 1, 1);   // 2048 blocks, XCD-swizzled
    dim3 block(D_DIM, 1, 1);
    local_enc_kernel<<<grid, block, 0, stream>>>(x, sz, sm, out, N);
}

// Round 19
// 104.562 us; speedup vs baseline: 1.0228x; 1.0228x over previous
//
#include <hip/hip_runtime.h>
#include <utility>

#define D_DIM 256
#define WID   33
#define CEN   16
#define RWAVE 32                   // rows per wave
#define RBLK  64                   // rows per block (2 row-groups x 2 col-halves)
#define WINW  65                   // window positions 0..64 (rel. to base)
#define PRE   49                   // head loads 0..48; row k issues 49+k

// R18 post-mortem: allocator targets MAX achievable occupancy (8 waves/EU =
// 64 VGPR) and spills the deeper window rather than use the 128-VGPR budget
// launch_bounds(256,4) permits. Measured occupancy is only ~3.3 waves/EU, so
// the squeeze buys nothing. Fix: amdgpu_waves_per_eu(4,4) — capping max
// waves at 4/EU makes 128 VGPR the allocator's own target; PRE=49 (17-row
// lookahead, ~8.7KB outstanding/wave) fits with no spill.

typedef float f32x2 __attribute__((ext_vector_type(2)));

__device__ __forceinline__ float rdlane(float v, int l) {
    return __uint_as_float(__builtin_amdgcn_readlane(__float_as_uint(v), l));
}

__device__ __forceinline__ int clampN(int p, int N) {
    return p < 0 ? 0 : (p >= N ? N - 1 : p);
}

__device__ __forceinline__ f32x2 ld2(const float* __restrict__ p) {
    return *(const f32x2*)p;
}

template <size_t... Is>
__device__ __forceinline__ void load_head(f32x2 (&W)[WINW],
                                          const float* __restrict__ xw,
                                          int base, int N,
                                          std::index_sequence<Is...>) {
    ((W[Is] = ld2(xw + (size_t)clampN(base + (int)Is, N) * D_DIM)), ...);
}

template <size_t... Rs>
__device__ __forceinline__ void load_w(float (&wvv)[RWAVE],
                                       const float* __restrict__ smb,
                                       int n0w, int minl,
                                       std::index_sequence<Rs...>) {
    ((wvv[Rs] = smb[(size_t)(n0w + (int)Rs) * WID + minl]), ...);
}

template <size_t... Rs>
__device__ __forceinline__ void zero_bad_w(float (&wvv)[RWAVE], int n0w, int lane,
                                           int N, std::index_sequence<Rs...>) {
    ((wvv[Rs] = ((unsigned)(n0w + (int)Rs - CEN + lane) < (unsigned)N)
                    ? wvv[Rs] : 0.0f),
     ...);
}

template <int K, size_t... Is>
__device__ __forceinline__ f32x2 dot_row(const f32x2 (&W)[WINW], float wrow,
                                         std::index_sequence<Is...>) {
    f32x2 a0 = {0.f, 0.f}, a1 = {0.f, 0.f}, a2 = {0.f, 0.f}, a3 = {0.f, 0.f};
    (([&] {
         const float ws = rdlane(wrow, (int)Is);
         const f32x2 xv = W[K + (int)Is];
         f32x2& ac = ((int)Is & 3) == 0 ? a0
                   : ((int)Is & 3) == 1 ? a1
                   : ((int)Is & 3) == 2 ? a2 : a3;
         ac.x = fmaf(xv.x, ws, ac.x);
         ac.y = fmaf(xv.y, ws, ac.y);
     }()),
     ...);
    return (a0 + a1) + (a2 + a3);
}

template <int K>
__device__ __forceinline__ void row_step(f32x2 (&W)[WINW], const float (&wvv)[RWAVE],
                                         float szv, float* __restrict__ ob,
                                         const float* __restrict__ xw,
                                         int base, int N) {
    if constexpr (PRE + K < WINW) {        // pipelined load, 17-row lookahead
        const int p = base + PRE + K;      // >= 33, only upper clamp needed
        W[PRE + K] = ld2(xw + (size_t)(p >= N ? N - 1 : p) * D_DIM);
    }
    __builtin_amdgcn_sched_barrier(0);     // pin: no sinking across rows
    const f32x2 s   = dot_row<K>(W, wvv[K], std::make_index_sequence<WID>{});
    const float inv = __builtin_amdgcn_rcpf(fmaxf(rdlane(szv, K), 1e-6f));
    f32x2 o;
    o.x = s.x * inv;
    o.y = s.y * inv;
    *(f32x2*)(ob + (size_t)K * D_DIM) = o;
}

template <size_t... Ks>
__device__ __forceinline__ void all_rows(f32x2 (&W)[WINW], const float (&wvv)[RWAVE],
                                         float szv, float* __restrict__ ob,
                                         const float* __restrict__ xw,
                                         int base, int N,
                                         std::index_sequence<Ks...>) {
    (row_step<(int)Ks>(W, wvv, szv, ob, xw, base, N), ...);
}

__global__ __launch_bounds__(256)
__attribute__((amdgpu_waves_per_eu(4, 4)))
void local_enc_kernel(
    const float* __restrict__ x, const float* __restrict__ sizev,
    const float* __restrict__ sm, float* __restrict__ out, int N) {
    // XCD swizzle: XCD k owns batch k, strips consecutive -> halo L2-local
    const int bid   = blockIdx.x;
    const int swz   = (bid & 7) * 256 + (bid >> 3);
    const int strip = swz & 255;
    const int b     = swz >> 8;
    const int n0    = strip * RBLK;
    const int tid   = threadIdx.x;
    const int wv    = tid >> 6;
    const int lane  = tid & 63;

    const int n0w = n0 + RWAVE * (wv >> 1);        // this wave's 32 rows
    const int cp  = ((wv & 1) * 64 + lane) * 2;    // this thread's column pair

    const size_t bN = (size_t)b * (size_t)N;
    const float* __restrict__ xw  = x   + bN * D_DIM + cp;
    float*       __restrict__ ob  = out + (bN + (size_t)n0w) * D_DIM + cp;
    const float* __restrict__ smb = sm    + bN * WID;
    const float* __restrict__ szb = sizev + bN;

    const int minl = (lane < WID) ? lane : (WID - 1);
    const float szv = szb[(n0w + minl < N) ? (n0w + minl) : (N - 1)];

    float wvv[RWAVE];
    load_w(wvv, smb, n0w, minl, std::make_index_sequence<RWAVE>{});
    if (n0w < CEN || n0w + RWAVE - 1 + CEN >= N)   // boundary waves only
        zero_bad_w(wvv, n0w, lane, N, std::make_index_sequence<RWAVE>{});

    const int base = n0w - CEN;
    f32x2 W[WINW];
    load_head(W, xw, base, N, std::make_index_sequence<PRE>{});

    __builtin_amdgcn_sched_barrier(0);
    all_rows(W, wvv, szv, ob, xw, base, N, std::make_index_sequence<RWAVE>{});
}

extern "C" void kernel_launch(void* const* d_in, const int* in_sizes, int n_in,
                              void* d_out, int out_size, void* d_ws, size_t ws_size,
                              hipStream_t stream) {
    const float* x  = (const float*)d_in[0];
    const float* sz = (const float*)d_in[1];
    const float* sm = (const float*)d_in[2];
    float* out = (float*)d_out;

    const int B = 8;
    const int N = 16384;

    dim3 grid((N / RBLK) * B, 1, 1);   // 2048 blocks, XCD-swizzled
    dim3 block(D_DIM, 1, 1);
    local_enc_kernel<<<grid, block, 0, stream>>>(x, sz, sm, out, N);
}

// Round 20
// 82.291 us; speedup vs baseline: 1.2996x; 1.2706x over previous
//
#include <hip/hip_runtime.h>
#include <utility>

#define D_DIM 256
#define WID   33
#define CEN   16
#define RACC  8                    // output rows per thread (scatter accs)
#define XROWS (RACC + WID - 1)     // 40 x-rows streamed per thread
#define RBLK  16                   // rows per block (2 row-groups x 2 col-halves)

// R19 concluded: allocator pins 64 VGPR; occupancy ~ 800/VGPR waves/CU;
// gather window needs >=66 live regs -> permanently wedged (best 75.4us).
// Scatter form: 8 f32x2 accumulators/thread, x rows stream through one
// register each and die immediately -> liveness ~44 regs, no spill, AND
// ~20 waves/CU (1.5x R17 TLP). Compiler free to hoist x loads (no pins).

typedef float f32x2 __attribute__((ext_vector_type(2)));

__device__ __forceinline__ float rdlane(float v, int l) {
    return __uint_as_float(__builtin_amdgcn_readlane(__float_as_uint(v), l));
}

__device__ __forceinline__ int clampN(int p, int N) {
    return p < 0 ? 0 : (p >= N ? N - 1 : p);
}

__device__ __forceinline__ f32x2 ld2(const float* __restrict__ p) {
    return *(const f32x2*)p;
}

template <size_t... Rs>
__device__ __forceinline__ void load_w(float (&wvv)[RACC],
                                       const float* __restrict__ smb,
                                       int n0w, int minl,
                                       std::index_sequence<Rs...>) {
    ((wvv[Rs] = smb[(size_t)(n0w + (int)Rs) * WID + minl]), ...);
}

template <size_t... Rs>
__device__ __forceinline__ void zero_bad_w(float (&wvv)[RACC], int n0w, int lane,
                                           int N, std::index_sequence<Rs...>) {
    ((wvv[Rs] = ((unsigned)(n0w + (int)Rs - CEN + lane) < (unsigned)N)
                    ? wvv[Rs] : 0.0f),
     ...);
}

template <int J, size_t... Rs>
__device__ __forceinline__ void consume_j(f32x2 (&acc)[RACC],
                                          const float (&wvv)[RACC], f32x2 xv,
                                          std::index_sequence<Rs...>) {
    (([&] {
         constexpr int r = (int)Rs;
         if constexpr (J - r >= 0 && J - r < WID) {
             const float ws = rdlane(wvv[r], J - r);
             acc[r].x = fmaf(xv.x, ws, acc[r].x);
             acc[r].y = fmaf(xv.y, ws, acc[r].y);
         }
     }()),
     ...);
}

template <size_t... Js>
__device__ __forceinline__ void stream_rows(f32x2 (&acc)[RACC],
                                            const float (&wvv)[RACC],
                                            const float* __restrict__ xw,
                                            int n0w, int N,
                                            std::index_sequence<Js...>) {
    (([&] {
         const int p = clampN(n0w - CEN + (int)Js, N);   // wave-uniform row
         const f32x2 xv = ld2(xw + (size_t)p * D_DIM);
         consume_j<(int)Js>(acc, wvv, xv, std::make_index_sequence<RACC>{});
     }()),
     ...);
}

template <size_t... Rs>
__device__ __forceinline__ void store_all(const f32x2 (&acc)[RACC], float szv,
                                          float* __restrict__ ob,
                                          std::index_sequence<Rs...>) {
    (([&] {
         constexpr int r = (int)Rs;
         const float inv = __builtin_amdgcn_rcpf(fmaxf(rdlane(szv, r), 1e-6f));
         f32x2 o;
         o.x = acc[r].x * inv;
         o.y = acc[r].y * inv;
         *(f32x2*)(ob + (size_t)r * D_DIM) = o;
     }()),
     ...);
}

__global__ __launch_bounds__(256) void local_enc_kernel(
    const float* __restrict__ x, const float* __restrict__ sizev,
    const float* __restrict__ sm, float* __restrict__ out, int N) {
    // XCD swizzle: XCD k owns batch k, strips consecutive -> halo L2-local
    const int bid   = blockIdx.x;
    const int swz   = (bid & 7) * 1024 + (bid >> 3);
    const int strip = swz & 1023;
    const int b     = swz >> 10;
    const int n0    = strip * RBLK;
    const int tid   = threadIdx.x;
    const int wv    = tid >> 6;
    const int lane  = tid & 63;

    const int n0w = n0 + (wv >> 1) * RACC;         // this wave's 8 rows
    const int cp  = ((wv & 1) * 64 + lane) * 2;    // this thread's column pair

    const size_t bN = (size_t)b * (size_t)N;
    const float* __restrict__ xw  = x   + bN * D_DIM + cp;
    float*       __restrict__ ob  = out + (bN + (size_t)n0w) * D_DIM + cp;
    const float* __restrict__ smb = sm    + bN * WID;
    const float* __restrict__ szb = sizev + bN;

    // lane-distributed weight rows (lane = tap) + sizes (lane&7 = row)
    const int minl = (lane < WID) ? lane : (WID - 1);
    const float szv = szb[n0w + (lane & 7)];       // n0w+7 <= N-1 always

    float wvv[RACC];
    load_w(wvv, smb, n0w, minl, std::make_index_sequence<RACC>{});
    if (n0w < CEN || n0w + RACC - 1 + CEN >= N)    // boundary waves only
        zero_bad_w(wvv, n0w, lane, N, std::make_index_sequence<RACC>{});

    f32x2 acc[RACC] = {};
    stream_rows(acc, wvv, xw, n0w, N, std::make_index_sequence<XROWS>{});
    store_all(acc, szv, ob, std::make_index_sequence<RACC>{});
}

extern "C" void kernel_launch(void* const* d_in, const int* in_sizes, int n_in,
                              void* d_out, int out_size, void* d_ws, size_t ws_size,
                              hipStream_t stream) {
    const float* x  = (const float*)d_in[0];
    const float* sz = (const float*)d_in[1];
    const float* sm = (const float*)d_in[2];
    float* out = (float*)d_out;

    const int B = 8;
    const int N = 16384;

    dim3 grid((N / RBLK) * B, 1, 1);   // 8192 blocks, XCD-swizzled
    dim3 block(D_DIM, 1, 1);
    local_enc_kernel<<<grid, block, 0, stream>>>(x, sz, sm, out, N);
}

// Round 21
// 72.339 us; speedup vs baseline: 1.4784x; 1.1376x over previous
//
#include <hip/hip_runtime.h>
#include <utility>

#define D_DIM 256
#define WID   33
#define CEN   16
#define RACC  8                    // output rows per thread (scatter accs)
#define XROWS (RACC + WID - 1)     // 40 x-rows streamed per thread
#define RBLK  16                   // output rows per block
#define XTILE (RBLK + 2 * CEN)     // 48 staged x rows (48 KB LDS)

// R20 concluded: in any register-staged form the allocator pins VGPR at
// 32-64 -> only ~4-6 loads in flight -> ~50us of exposed latency (VALUBusy
// 38%). global_load_lds is the one mechanism whose in-flight data costs no
// VGPRs: each block DMAs its 48-row x tile into LDS (one dwordx4 instr
// stages a full 256-float row), one barrier, then the proven scatter
// compute streams rows from LDS via ds_read_b64 (lgkm-pipelined, ~0 stall).

typedef float f32x2 __attribute__((ext_vector_type(2)));

__device__ __forceinline__ float rdlane(float v, int l) {
    return __uint_as_float(__builtin_amdgcn_readlane(__float_as_uint(v), l));
}

__device__ __forceinline__ int clampN(int p, int N) {
    return p < 0 ? 0 : (p >= N ? N - 1 : p);
}

__device__ __forceinline__ f32x2 ld2(const float* p) {
    return *(const f32x2*)p;
}

// stage 12 rows per wave: lane l supplies bytes [16l, 16l+16) of the row
template <size_t... Ss>
__device__ __forceinline__ void stage_rows(float* xs,
                                           const float* __restrict__ xlane,
                                           int base, int N, int wv,
                                           std::index_sequence<Ss...>) {
    (([&] {
         const int s = wv * (XTILE / 4) + (int)Ss;
         const int p = clampN(base + s, N);
         __builtin_amdgcn_global_load_lds(
             (const __attribute__((address_space(1))) void*)(xlane +
                                                             (size_t)p * D_DIM),
             (__attribute__((address_space(3))) void*)(xs + s * D_DIM),
             16, 0, 0);
     }()),
     ...);
}

template <size_t... Rs>
__device__ __forceinline__ void load_w(float (&wvv)[RACC],
                                       const float* __restrict__ smb,
                                       int n0w, int minl,
                                       std::index_sequence<Rs...>) {
    ((wvv[Rs] = smb[(size_t)(n0w + (int)Rs) * WID + minl]), ...);
}

template <size_t... Rs>
__device__ __forceinline__ void zero_bad_w(float (&wvv)[RACC], int n0w, int lane,
                                           int N, std::index_sequence<Rs...>) {
    ((wvv[Rs] = ((unsigned)(n0w + (int)Rs - CEN + lane) < (unsigned)N)
                    ? wvv[Rs] : 0.0f),
     ...);
}

template <int J, size_t... Rs>
__device__ __forceinline__ void consume_j(f32x2 (&acc)[RACC],
                                          const float (&wvv)[RACC], f32x2 xv,
                                          std::index_sequence<Rs...>) {
    (([&] {
         constexpr int r = (int)Rs;
         if constexpr (J - r >= 0 && J - r < WID) {
             const float ws = rdlane(wvv[r], J - r);
             acc[r].x = fmaf(xv.x, ws, acc[r].x);
             acc[r].y = fmaf(xv.y, ws, acc[r].y);
         }
     }()),
     ...);
}

template <size_t... Js>
__device__ __forceinline__ void stream_rows(f32x2 (&acc)[RACC],
                                            const float (&wvv)[RACC],
                                            const float* xsL,
                                            std::index_sequence<Js...>) {
    (([&] {
         const f32x2 xv = ld2(xsL + (size_t)((int)Js) * D_DIM);
         consume_j<(int)Js>(acc, wvv, xv, std::make_index_sequence<RACC>{});
     }()),
     ...);
}

template <size_t... Rs>
__device__ __forceinline__ void store_all(const f32x2 (&acc)[RACC], float szv,
                                          float* __restrict__ ob,
                                          std::index_sequence<Rs...>) {
    (([&] {
         constexpr int r = (int)Rs;
         const float inv = __builtin_amdgcn_rcpf(fmaxf(rdlane(szv, r), 1e-6f));
         f32x2 o;
         o.x = acc[r].x * inv;
         o.y = acc[r].y * inv;
         *(f32x2*)(ob + (size_t)r * D_DIM) = o;
     }()),
     ...);
}

__global__ __launch_bounds__(256) void local_enc_kernel(
    const float* __restrict__ x, const float* __restrict__ sizev,
    const float* __restrict__ sm, float* __restrict__ out, int N) {
    __shared__ float xs[XTILE * D_DIM];    // 48 rows x 1KB = 48 KB

    // XCD swizzle: XCD k owns batch k, strips consecutive -> halo L2-local
    const int bid   = blockIdx.x;
    const int swz   = (bid & 7) * 1024 + (bid >> 3);
    const int strip = swz & 1023;
    const int b     = swz >> 10;
    const int n0    = strip * RBLK;
    const int tid   = threadIdx.x;
    const int wv    = tid >> 6;
    const int lane  = tid & 63;

    const size_t bN = (size_t)b * (size_t)N;

    // ---- async DMA: stage 48 clamped x rows into LDS ----
    const int base = n0 - CEN;
    stage_rows(xs, x + bN * D_DIM + lane * 4, base, N, wv,
               std::make_index_sequence<XTILE / 4>{});

    // ---- weights + sizes (register-resident, readlane-shared) ----
    const int n0w = n0 + (wv >> 1) * RACC;         // this wave's 8 rows
    const int cp  = ((wv & 1) * 64 + lane) * 2;    // this thread's column pair

    const float* __restrict__ smb = sm    + bN * WID;
    const float* __restrict__ szb = sizev + bN;
    const int minl = (lane < WID) ? lane : (WID - 1);
    const float szv = szb[n0w + (lane & 7)];       // n0w+7 <= N-1 always

    float wvv[RACC];
    load_w(wvv, smb, n0w, minl, std::make_index_sequence<RACC>{});
    if (n0w < CEN || n0w + RACC - 1 + CEN >= N)    // boundary waves only
        zero_bad_w(wvv, n0w, lane, N, std::make_index_sequence<RACC>{});

    __syncthreads();   // drains the global_load_lds queue (vmcnt) + barrier

    // ---- scatter compute from LDS ----
    const int lstart = (wv >> 1) * RACC;           // window start in tile
    f32x2 acc[RACC] = {};
    stream_rows(acc, wvv, xs + lstart * D_DIM + cp,
                std::make_index_sequence<XROWS>{});

    float* __restrict__ ob = out + (bN + (size_t)n0w) * D_DIM + cp;
    store_all(acc, szv, ob, std::make_index_sequence<RACC>{});
}

extern "C" void kernel_launch(void* const* d_in, const int* in_sizes, int n_in,
                              void* d_out, int out_size, void* d_ws, size_t ws_size,
                              hipStream_t stream) {
    const float* x  = (const float*)d_in[0];
    const float* sz = (const float*)d_in[1];
    const float* sm = (const float*)d_in[2];
    float* out = (float*)d_out;

    const int B = 8;
    const int N = 16384;

    dim3 grid((N / RBLK) * B, 1, 1);   // 8192 blocks, XCD-swizzled
    dim3 block(D_DIM, 1, 1);
    local_enc_kernel<<<grid, block, 0, stream>>>(x, sz, sm, out, N);
}

// Round 22
// 70.384 us; speedup vs baseline: 1.5194x; 1.0278x over previous
//
#include <hip/hip_runtime.h>
#include <utility>

#define D_DIM  256
#define BLKT   512                 // threads per block (8 waves)
#define WID    33
#define CEN    16
#define RACC   8                   // output rows per thread (scatter accs)
#define XROWS  (RACC + WID - 1)    // 40 x-rows streamed per thread
#define RBLK   32                  // output rows per block
#define XTILE  (RBLK + 2 * CEN)    // 64 staged x rows (64 KB LDS)

// R21 (72.3us): global_load_lds + LDS scatter works; limiters were 30%
// occupancy (48KB tile -> 3 blocks/CU) and 3x halo staging for 16 output
// rows. This round: 512-thread blocks, RBLK=32, 64KB tile -> 2 blocks/CU
// = 16 waves/CU, halo 2x, twice the compute per vmcnt-drain. Same scatter
// core (8 f32x2 accs, readlane weights), clamp edges, XCD swizzle.

typedef float f32x2 __attribute__((ext_vector_type(2)));

__device__ __forceinline__ float rdlane(float v, int l) {
    return __uint_as_float(__builtin_amdgcn_readlane(__float_as_uint(v), l));
}

__device__ __forceinline__ int clampN(int p, int N) {
    return p < 0 ? 0 : (p >= N ? N - 1 : p);
}

__device__ __forceinline__ f32x2 ld2(const float* p) {
    return *(const f32x2*)p;
}

// stage 8 rows per wave: lane l supplies bytes [16l, 16l+16) of the row
template <size_t... Ss>
__device__ __forceinline__ void stage_rows(float* xs,
                                           const float* __restrict__ xlane,
                                           int base, int N, int wv,
                                           std::index_sequence<Ss...>) {
    (([&] {
         const int s = wv * (XTILE / 8) + (int)Ss;
         const int p = clampN(base + s, N);
         __builtin_amdgcn_global_load_lds(
             (const __attribute__((address_space(1))) void*)(xlane +
                                                             (size_t)p * D_DIM),
             (__attribute__((address_space(3))) void*)(xs + s * D_DIM),
             16, 0, 0);
     }()),
     ...);
}

template <size_t... Rs>
__device__ __forceinline__ void load_w(float (&wvv)[RACC],
                                       const float* __restrict__ smb,
                                       int n0w, int minl,
                                       std::index_sequence<Rs...>) {
    ((wvv[Rs] = smb[(size_t)(n0w + (int)Rs) * WID + minl]), ...);
}

template <size_t... Rs>
__device__ __forceinline__ void zero_bad_w(float (&wvv)[RACC], int n0w, int lane,
                                           int N, std::index_sequence<Rs...>) {
    ((wvv[Rs] = ((unsigned)(n0w + (int)Rs - CEN + lane) < (unsigned)N)
                    ? wvv[Rs] : 0.0f),
     ...);
}

template <int J, size_t... Rs>
__device__ __forceinline__ void consume_j(f32x2 (&acc)[RACC],
                                          const float (&wvv)[RACC], f32x2 xv,
                                          std::index_sequence<Rs...>) {
    (([&] {
         constexpr int r = (int)Rs;
         if constexpr (J - r >= 0 && J - r < WID) {
             const float ws = rdlane(wvv[r], J - r);
             acc[r].x = fmaf(xv.x, ws, acc[r].x);
             acc[r].y = fmaf(xv.y, ws, acc[r].y);
         }
     }()),
     ...);
}

template <size_t... Js>
__device__ __forceinline__ void stream_rows(f32x2 (&acc)[RACC],
                                            const float (&wvv)[RACC],
                                            const float* xsL,
                                            std::index_sequence<Js...>) {
    (([&] {
         const f32x2 xv = ld2(xsL + (size_t)((int)Js) * D_DIM);
         consume_j<(int)Js>(acc, wvv, xv, std::make_index_sequence<RACC>{});
     }()),
     ...);
}

template <size_t... Rs>
__device__ __forceinline__ void store_all(const f32x2 (&acc)[RACC], float szv,
                                          float* __restrict__ ob,
                                          std::index_sequence<Rs...>) {
    (([&] {
         constexpr int r = (int)Rs;
         const float inv = __builtin_amdgcn_rcpf(fmaxf(rdlane(szv, r), 1e-6f));
         f32x2 o;
         o.x = acc[r].x * inv;
         o.y = acc[r].y * inv;
         *(f32x2*)(ob + (size_t)r * D_DIM) = o;
     }()),
     ...);
}

__global__ __launch_bounds__(BLKT) void local_enc_kernel(
    const float* __restrict__ x, const float* __restrict__ sizev,
    const float* __restrict__ sm, float* __restrict__ out, int N) {
    __shared__ float xs[XTILE * D_DIM];    // 64 rows x 1KB = 64 KB

    // XCD swizzle: XCD k owns batch k, strips consecutive -> halo L2-local
    const int bid   = blockIdx.x;
    const int swz   = (bid & 7) * 512 + (bid >> 3);
    const int strip = swz & 511;
    const int b     = swz >> 9;
    const int n0    = strip * RBLK;
    const int tid   = threadIdx.x;
    const int wv    = tid >> 6;            // 0..7: 4 row-groups x 2 col-halves
    const int lane  = tid & 63;

    const size_t bN = (size_t)b * (size_t)N;

    // ---- async DMA: stage 64 clamped x rows into LDS ----
    const int base = n0 - CEN;
    stage_rows(xs, x + bN * D_DIM + lane * 4, base, N, wv,
               std::make_index_sequence<XTILE / 8>{});

    // ---- weights + sizes (register-resident, readlane-shared) ----
    const int n0w = n0 + (wv >> 1) * RACC;         // this wave's 8 rows
    const int cp  = ((wv & 1) * 64 + lane) * 2;    // this thread's column pair

    const float* __restrict__ smb = sm    + bN * WID;
    const float* __restrict__ szb = sizev + bN;
    const int minl = (lane < WID) ? lane : (WID - 1);
    const float szv = szb[n0w + (lane & 7)];       // n0w+7 <= N-1 always

    float wvv[RACC];
    load_w(wvv, smb, n0w, minl, std::make_index_sequence<RACC>{});
    if (n0w < CEN || n0w + RACC - 1 + CEN >= N)    // boundary waves only
        zero_bad_w(wvv, n0w, lane, N, std::make_index_sequence<RACC>{});

    __syncthreads();   // drains the global_load_lds queue (vmcnt) + barrier

    // ---- scatter compute from LDS ----
    const int lstart = (wv >> 1) * RACC;           // window start in tile
    f32x2 acc[RACC] = {};
    stream_rows(acc, wvv, xs + lstart * D_DIM + cp,
                std::make_index_sequence<XROWS>{});

    float* __restrict__ ob = out + (bN + (size_t)n0w) * D_DIM + cp;
    store_all(acc, szv, ob, std::make_index_sequence<RACC>{});
}

extern "C" void kernel_launch(void* const* d_in, const int* in_sizes, int n_in,
                              void* d_out, int out_size, void* d_ws, size_t ws_size,
                              hipStream_t stream) {
    const float* x  = (const float*)d_in[0];
    const float* sz = (const float*)d_in[1];
    const float* sm = (const float*)d_in[2];
    float* out = (float*)d_out;

    const int B = 8;
    const int N = 16384;

    dim3 grid((N / RBLK) * B, 1, 1);   // 4096 blocks, XCD-swizzled
    dim3 block(BLKT, 1, 1);
    local_enc_kernel<<<grid, block, 0, stream>>>(x, sz, sm, out, N);
}

// Round 23
// 63.124 us; speedup vs baseline: 1.6942x; 1.1150x over previous
//
#include <hip/hip_runtime.h>
#include <utility>

#define D_DIM 256
#define WID   33
#define CEN   16
#define RACC  8                    // output rows per thread
#define XROWS (RACC + 2 * CEN)     // 40 x-rows streamed per thread
#define RITER 16                   // output rows per iteration
#define NI    16                   // iterations per block
#define CHUNK (RITER * NI)         // 256 output rows per block
#define RING  64                   // ring rows = 64 KB LDS
#define PROL  48                   // prologue staged rows

// R22 (70.4us) post-mortem: single-shot [stage->drain->compute] blocks only
// overlap pairwise (~50% duty) and stage 2x halo. This kernel: persistent
// block over 256 rows, 64-row LDS ring, T3 2-phase schedule per 16-row iter:
// issue DMA(t+1) + prefetch weights(t+1) -> sched_barrier -> compute(t) ->
// __syncthreads (vmcnt drain lands AFTER compute). Each row staged ~once.
// Ring slots compile-time via 4-phase unroll (16m mod 64 has period 4).

typedef float f32x2 __attribute__((ext_vector_type(2)));

__device__ __forceinline__ float rdlane(float v, int l) {
    return __uint_as_float(__builtin_amdgcn_readlane(__float_as_uint(v), l));
}

__device__ __forceinline__ int clampN(int p, int N) {
    return p < 0 ? 0 : (p >= N ? N - 1 : p);
}

__device__ __forceinline__ f32x2 ld2(const float* p) {
    return *(const f32x2*)p;
}

__device__ __forceinline__ void dma_row(float* xs, int slot,
                                        const float* __restrict__ xlane,
                                        int row) {
    __builtin_amdgcn_global_load_lds(
        (const __attribute__((address_space(1))) void*)(xlane +
                                                        (size_t)row * D_DIM),
        (__attribute__((address_space(3))) void*)(xs + slot * D_DIM), 16, 0, 0);
}

template <size_t... Ss>
__device__ __forceinline__ void stage_prol(float* xs,
                                           const float* __restrict__ xlane,
                                           int base0, int N, int wv,
                                           std::index_sequence<Ss...>) {
    (([&] {
         const int s = wv * (PROL / 4) + (int)Ss;
         dma_row(xs, s, xlane, clampN(base0 + s, N));
     }()),
     ...);
}

template <int PH, size_t... Ss>
__device__ __forceinline__ void stage_iter(float* xs,
                                           const float* __restrict__ xlane,
                                           int base0, int m, int N, int wv,
                                           std::index_sequence<Ss...>) {
    (([&] {
         constexpr int C = (PROL + 16 * PH) & (RING - 1);
         const int j = wv * 4 + (int)Ss;
         dma_row(xs, C + j, xlane, clampN(base0 + PROL + 16 * m + j, N));
     }()),
     ...);
}

template <size_t... Rs>
__device__ __forceinline__ void load_w(float (&w)[RACC],
                                       const float* __restrict__ smb,
                                       int nbase, int minl, int N,
                                       std::index_sequence<Rs...>) {
    ((w[Rs] = smb[(size_t)clampN(nbase + (int)Rs, N) * WID + minl]), ...);
}

template <size_t... Rs>
__device__ __forceinline__ void zero_bad_w(float (&w)[RACC], int n0w, int lane,
                                           int N, std::index_sequence<Rs...>) {
    ((w[Rs] = ((unsigned)(n0w + (int)Rs - CEN + lane) < (unsigned)N)
                  ? w[Rs] : 0.0f),
     ...);
}

template <int J, size_t... Rs>
__device__ __forceinline__ void consume_j(f32x2 (&acc)[RACC],
                                          const float (&w)[RACC], f32x2 xv,
                                          std::index_sequence<Rs...>) {
    (([&] {
         constexpr int r = (int)Rs;
         if constexpr (J - r >= 0 && J - r < WID) {
             const float ws = rdlane(w[r], J - r);
             acc[r].x = fmaf(xv.x, ws, acc[r].x);
             acc[r].y = fmaf(xv.y, ws, acc[r].y);
         }
     }()),
     ...);
}

template <int PH, int RG, size_t... Js>
__device__ __forceinline__ void stream_rows(f32x2 (&acc)[RACC],
                                            const float (&w)[RACC],
                                            const float* xscp,
                                            std::index_sequence<Js...>) {
    (([&] {
         constexpr int slot = (16 * PH + 8 * RG + (int)Js) & (RING - 1);
         const f32x2 xv = ld2(xscp + slot * D_DIM);
         consume_j<(int)Js>(acc, w, xv, std::make_index_sequence<RACC>{});
     }()),
     ...);
}

template <size_t... Rs>
__device__ __forceinline__ void store_all(const f32x2 (&acc)[RACC], float szv,
                                          float* __restrict__ ob,
                                          std::index_sequence<Rs...>) {
    (([&] {
         constexpr int r = (int)Rs;
         const float inv = __builtin_amdgcn_rcpf(fmaxf(rdlane(szv, r), 1e-6f));
         f32x2 o;
         o.x = acc[r].x * inv;
         o.y = acc[r].y * inv;
         *(f32x2*)(ob + (size_t)r * D_DIM) = o;
     }()),
     ...);
}

template <int PH>
__device__ __forceinline__ void iter_body(
    float* xs, const float* __restrict__ xlane, const float* __restrict__ smb,
    const float* __restrict__ szb, float* __restrict__ obcp, int n0, int m,
    int N, int wv, int rg, int lane, int cp, float (&wcur)[RACC],
    float (&wnxt)[RACC], float& szcur, float& sznxt, int minl) {
    // phase 1: issue next-tile DMA + next-iter weight/size prefetch
    if (m < NI - 1)
        stage_iter<PH>(xs, xlane, n0 - CEN, m, N, wv,
                       std::make_index_sequence<4>{});
    const int n1 = n0 + (m + 1) * RITER + rg * RACC;
    load_w(wnxt, smb, n1, minl, N, std::make_index_sequence<RACC>{});
    sznxt = szb[clampN(n1 + (lane & 7), N)];
    __builtin_amdgcn_sched_barrier(0);

    // phase 2: compute current 16 rows from the ring
    const int n0w = n0 + m * RITER + rg * RACC;
    if (n0w < CEN || n0w + RACC - 1 + CEN >= N)      // boundary iters only
        zero_bad_w(wcur, n0w, lane, N, std::make_index_sequence<RACC>{});

    f32x2 acc[RACC] = {};
    if (rg == 0)
        stream_rows<PH, 0>(acc, wcur, xs + cp, std::make_index_sequence<XROWS>{});
    else
        stream_rows<PH, 1>(acc, wcur, xs + cp, std::make_index_sequence<XROWS>{});

    store_all(acc, szcur, obcp + (size_t)n0w * D_DIM,
              std::make_index_sequence<RACC>{});
    __syncthreads();   // vmcnt(0)+lgkmcnt(0) drain AFTER compute, then barrier
}

__global__ __launch_bounds__(256) void local_enc_kernel(
    const float* __restrict__ x, const float* __restrict__ sizev,
    const float* __restrict__ sm, float* __restrict__ out, int N) {
    __shared__ float xs[RING * D_DIM];     // 64 rows x 1KB = 64 KB

    // XCD swizzle: XCD k owns batch k, strips consecutive -> L2-local
    const int bid   = blockIdx.x;
    const int swz   = (bid & 7) * 64 + (bid >> 3);
    const int strip = swz & 63;
    const int b     = swz >> 6;
    const int n0    = strip * CHUNK;
    const int tid   = threadIdx.x;
    const int wv    = tid >> 6;            // 0..3: 2 row-groups x 2 col-halves
    const int lane  = tid & 63;
    const int rg    = wv >> 1;
    const int cp    = ((wv & 1) * 64 + lane) * 2;

    const size_t bN = (size_t)b * (size_t)N;
    const float* __restrict__ xlane = x + bN * D_DIM + lane * 4;
    const float* __restrict__ smb   = sm + bN * WID;
    const float* __restrict__ szb   = sizev + bN;
    float* __restrict__ obcp        = out + bN * D_DIM + cp;

    // prologue: stage first 48 rows + load iter-0 weights/sizes
    stage_prol(xs, xlane, n0 - CEN, N, wv, std::make_index_sequence<PROL / 4>{});
    const int minl = (lane < WID) ? lane : (WID - 1);
    float wA[RACC], wB[RACC];
    float szA, szB;
    load_w(wA, smb, n0 + rg * RACC, minl, N, std::make_index_sequence<RACC>{});
    szA = szb[clampN(n0 + rg * RACC + (lane & 7), N)];
    __syncthreads();

#pragma unroll 1
    for (int mo = 0; mo < NI / 4; ++mo) {
        const int m0 = 4 * mo;
        iter_body<0>(xs, xlane, smb, szb, obcp, n0, m0 + 0, N, wv, rg, lane,
                     cp, wA, wB, szA, szB, minl);
        iter_body<1>(xs, xlane, smb, szb, obcp, n0, m0 + 1, N, wv, rg, lane,
                     cp, wB, wA, szB, szA, minl);
        iter_body<2>(xs, xlane, smb, szb, obcp, n0, m0 + 2, N, wv, rg, lane,
                     cp, wA, wB, szA, szB, minl);
        iter_body<3>(xs, xlane, smb, szb, obcp, n0, m0 + 3, N, wv, rg, lane,
                     cp, wB, wA, szB, szA, minl);
    }
}

extern "C" void kernel_launch(void* const* d_in, const int* in_sizes, int n_in,
                              void* d_out, int out_size, void* d_ws, size_t ws_size,
                              hipStream_t stream) {
    const float* x  = (const float*)d_in[0];
    const float* sz = (const float*)d_in[1];
    const float* sm = (const float*)d_in[2];
    float* out = (float*)d_out;

    const int B = 8;
    const int N = 16384;

    dim3 grid((N / CHUNK) * B, 1, 1);   // 64 x 8 = 512 blocks, XCD-swizzled
    dim3 block(256, 1, 1);
    local_enc_kernel<<<grid, block, 0, stream>>>(x, sz, sm, out, N);
}